// Round 2
// baseline (222.187 us; speedup 1.0000x reference)
//
#include <hip/hip_runtime.h>

#define BATCH 32
#define I_TOT 4096
#define N_CAP 16
#define D_CAP 16
#define K_DIM 128
#define RCHUNK 128
#define NCHUNK_R (I_TOT / RCHUNK)   // 32

// ws layout (floats):
//   colsum: [B][128]               off 0       size 4096
//   w_o:    [B][16][128]           off 4096    size 65536
//   sp:     [B][nslots][2048]      off 69632   size B*nslots*2048 (nslots<=32)
#define WS_COLSUM 0
#define WS_WO 4096
#define WS_SP 69632

// ---------------------------------------------------------------------------
// K1: colsum[b][k] = sum_i u[b,i,k].  grid (32, B), block 256.
__global__ __launch_bounds__(256) void colsum_kernel(const float* __restrict__ u,
                                                     float* __restrict__ ws) {
    const int b = blockIdx.y;
    const int c0 = blockIdx.x * 128;
    const int t = threadIdx.x;
    const int k4 = t & 31;
    const int rg = t >> 5;          // 0..7

    const float4* up = (const float4*)u + ((size_t)b * I_TOT + c0 + rg) * 32 + k4;
    float4 acc = {0.f, 0.f, 0.f, 0.f};
    #pragma unroll
    for (int i = 0; i < 16; i++) {       // rows rg + i*8
        float4 v = up[(size_t)i * 256];  // 8 rows * 32 float4
        acc.x += v.x; acc.y += v.y; acc.z += v.z; acc.w += v.w;
    }
    __shared__ __align__(16) float4 red[8][32];
    red[rg][k4] = acc;
    __syncthreads();
    if (t < 32) {
        float4 s = red[0][t];
        #pragma unroll
        for (int r = 1; r < 8; r++) {
            float4 v = red[r][t];
            s.x += v.x; s.y += v.y; s.z += v.z; s.w += v.w;
        }
        atomicAdd(&ws[WS_COLSUM + b * K_DIM + t * 4 + 0], s.x);
        atomicAdd(&ws[WS_COLSUM + b * K_DIM + t * 4 + 1], s.y);
        atomicAdd(&ws[WS_COLSUM + b * K_DIM + t * 4 + 2], s.z);
        atomicAdd(&ws[WS_COLSUM + b * K_DIM + t * 4 + 3], s.w);
    }
}

// ---------------------------------------------------------------------------
// K2: update. mode 0: o from colsum/16, l2norm, write w_o.
//             mode 1: o from sp-reduce, l2norm, write w_o, re-zero sp (atomic path).
//             mode 2: o from sp-reduce, squash -> out.
__global__ __launch_bounds__(256) void update_kernel(const float* __restrict__ W,
                                                     float* __restrict__ ws,
                                                     float* __restrict__ out,
                                                     int mode, int nslots) {
    const int b = blockIdx.x;
    const int t = threadIdx.x;
    const int n = t >> 4;
    const int d = t & 15;

    __shared__ float s_lds[N_CAP][K_DIM + 2];   // stride 130: no 4-way bank conflict
    __shared__ float o_s[N_CAP][D_CAP];

    if (mode != 0) {
        float* sp = ws + WS_SP + (size_t)b * nslots * 2048;
        #pragma unroll
        for (int j = 0; j < 8; j++) {
            int idx = t + j * 256;
            float acc = 0.f;
            #pragma unroll 8
            for (int ch = 0; ch < nslots; ch++) acc += sp[(size_t)ch * 2048 + idx];
            s_lds[idx >> 7][idx & 127] = acc;
        }
        if (mode == 1 && nslots < NCHUNK_R) {
            #pragma unroll
            for (int j = 0; j < 8; j++) {
                int idx = t + j * 256;
                for (int ch = 0; ch < nslots; ch++) sp[(size_t)ch * 2048 + idx] = 0.f;
            }
        }
        __syncthreads();
    }

    float o = 0.f;
    if (mode == 0) {
        const float* src = ws + WS_COLSUM + b * K_DIM;
        #pragma unroll 8
        for (int k = 0; k < K_DIM; k++) o += src[k] * W[k * 256 + t];
        o *= (1.f / 16.f);
    } else {
        #pragma unroll 8
        for (int k = 0; k < K_DIM; k++) o += s_lds[n][k] * W[k * 256 + t];
    }

    o_s[n][d] = o;
    __syncthreads();

    if (mode == 2) {
        float ss = 1e-7f;  // EPS
        #pragma unroll
        for (int j = 0; j < 16; j++) { float v = o_s[n][j]; ss += v * v; }
        float scale = sqrtf(ss) / (0.5f + ss);
        out[b * 256 + t] = scale * o;
        return;
    }

    float ss = 0.f;
    #pragma unroll
    for (int j = 0; j < 16; j++) { float v = o_s[n][j]; ss += v * v; }
    float on = o * rsqrtf(fmaxf(ss, 1e-12f));
    __syncthreads();
    o_s[n][d] = on;
    __syncthreads();

    // w_o[b][nn][k] = sum_d W[k][nn*16+d] * o_s[nn][d]
    float* w_o = ws + WS_WO;
    #pragma unroll
    for (int j = 0; j < 8; j++) {
        int idx = t + j * 256;      // 0..2047; nn = idx>>7, k = idx&127
        int nn = idx >> 7;
        int k = idx & 127;
        const float* wrow = W + k * 256 + nn * 16;
        float acc = 0.f;
        #pragma unroll
        for (int dd = 0; dd < 16; dd++) acc += wrow[dd] * o_s[nn][dd];
        w_o[(size_t)b * 2048 + idx] = acc;
    }
}

// ---------------------------------------------------------------------------
// K3: one routing pass, 128 rows per block. grid (32, B), block 256.
__global__ __launch_bounds__(256) void routing_kernel(const float* __restrict__ u,
                                                      float* __restrict__ ws,
                                                      int nslots) {
    const int b = blockIdx.y;
    const int chunk = blockIdx.x;
    const int i0 = chunk * RCHUNK;
    const int t = threadIdx.x;

    __shared__ __align__(16) float wo_s[N_CAP][K_DIM];   // 8 KiB
    __shared__ __align__(16) float c_s[RCHUNK][N_CAP];   // 8 KiB

    const float* w_o = ws + WS_WO + (size_t)b * 2048;
    #pragma unroll
    for (int j = 0; j < 8; j++) {
        int idx = t + j * 256;
        ((float*)wo_s)[idx] = w_o[idx];
    }
    __syncthreads();

    // ---- phase 1: 2 threads per row (k-halves), shuffle-reduce ----
    {
        const int row = t >> 1;
        const int h = t & 1;
        const float4* up = (const float4*)(u + ((size_t)b * I_TOT + i0 + row) * K_DIM + h * 64);
        const float4* wp = (const float4*)&wo_s[0][h * 64];
        float logit[16];
        #pragma unroll
        for (int n = 0; n < 16; n++) logit[n] = 0.f;
        #pragma unroll
        for (int q = 0; q < 16; q++) {
            float4 v = up[q];
            #pragma unroll
            for (int n = 0; n < 16; n++) {
                float4 w = wp[n * 32 + q];   // wo_s[n][h*64 + q*4]
                logit[n] += v.x * w.x + v.y * w.y + v.z * w.z + v.w * w.w;
            }
        }
        #pragma unroll
        for (int n = 0; n < 16; n++) logit[n] += __shfl_xor(logit[n], 1);

        float m = logit[0];
        #pragma unroll
        for (int n = 1; n < 16; n++) m = fmaxf(m, logit[n]);
        float sum = 0.f;
        #pragma unroll
        for (int n = 0; n < 16; n++) { logit[n] = __expf(logit[n] - m); sum += logit[n]; }
        float inv = 1.f / sum;

        float4* crow = (float4*)&c_s[row][h * 8];
        if (h == 0) {
            crow[0] = make_float4(logit[0] * inv, logit[1] * inv, logit[2] * inv, logit[3] * inv);
            crow[1] = make_float4(logit[4] * inv, logit[5] * inv, logit[6] * inv, logit[7] * inv);
        } else {
            crow[0] = make_float4(logit[8] * inv, logit[9] * inv, logit[10] * inv, logit[11] * inv);
            crow[1] = make_float4(logit[12] * inv, logit[13] * inv, logit[14] * inv, logit[15] * inv);
        }
    }
    __syncthreads();

    // ---- phase 2: float4 k-parallel accumulation, 2 capsules per thread ----
    const int k4 = t & 31;
    const int ng = t >> 5;   // 0..7 -> capsules {2ng, 2ng+1}
    float4 a0 = {0.f, 0.f, 0.f, 0.f}, a1 = {0.f, 0.f, 0.f, 0.f};
    const float4* up2 = (const float4*)(u + ((size_t)b * I_TOT + i0) * K_DIM) + k4;
    #pragma unroll 8
    for (int i = 0; i < RCHUNK; i++) {
        float4 v = up2[(size_t)i * 32];
        float2 c2 = *(const float2*)&c_s[i][ng * 2];
        a0.x += v.x * c2.x; a0.y += v.y * c2.x; a0.z += v.z * c2.x; a0.w += v.w * c2.x;
        a1.x += v.x * c2.y; a1.y += v.y * c2.y; a1.z += v.z * c2.y; a1.w += v.w * c2.y;
    }

    float* sp = ws + WS_SP;
    if (nslots == NCHUNK_R) {
        float4* dst = (float4*)(sp + (size_t)(b * NCHUNK_R + chunk) * 2048);
        dst[(ng * 2 + 0) * 32 + k4] = a0;
        dst[(ng * 2 + 1) * 32 + k4] = a1;
    } else {
        int slot = chunk % nslots;
        float* dst = sp + (size_t)(b * nslots + slot) * 2048;
        atomicAdd(&dst[(ng * 2 + 0) * K_DIM + k4 * 4 + 0], a0.x);
        atomicAdd(&dst[(ng * 2 + 0) * K_DIM + k4 * 4 + 1], a0.y);
        atomicAdd(&dst[(ng * 2 + 0) * K_DIM + k4 * 4 + 2], a0.z);
        atomicAdd(&dst[(ng * 2 + 0) * K_DIM + k4 * 4 + 3], a0.w);
        atomicAdd(&dst[(ng * 2 + 1) * K_DIM + k4 * 4 + 0], a1.x);
        atomicAdd(&dst[(ng * 2 + 1) * K_DIM + k4 * 4 + 1], a1.y);
        atomicAdd(&dst[(ng * 2 + 1) * K_DIM + k4 * 4 + 2], a1.z);
        atomicAdd(&dst[(ng * 2 + 1) * K_DIM + k4 * 4 + 3], a1.w);
    }
}

// ---------------------------------------------------------------------------
extern "C" void kernel_launch(void* const* d_in, const int* in_sizes, int n_in,
                              void* d_out, int out_size, void* d_ws, size_t ws_size,
                              hipStream_t stream) {
    const float* u = (const float*)d_in[0];   // (32, 4096, 128) f32
    const float* W = (const float*)d_in[1];   // (128, 256) f32
    float* out = (float*)d_out;               // (32, 16, 16) f32
    float* ws = (float*)d_ws;

    // how many per-chunk partial slots fit in ws?
    size_t avail = ws_size / 4;
    size_t full_need = (size_t)WS_SP + (size_t)BATCH * NCHUNK_R * 2048;
    int nslots;
    if (avail >= full_need) {
        nslots = NCHUNK_R;
    } else {
        size_t per = (size_t)BATCH * 2048;
        size_t rem = (avail > (size_t)WS_SP) ? (avail - WS_SP) / per : 1;
        if (rem < 1) rem = 1;
        if (rem > (size_t)NCHUNK_R) rem = NCHUNK_R;
        nslots = (int)rem;
    }

    // zero colsum (+ sp region when the atomic fallback is in use)
    size_t zero_floats = 4096 + ((nslots < NCHUNK_R) ? (size_t)BATCH * nslots * 2048 : 0);
    hipMemsetAsync(d_ws, 0, zero_floats * sizeof(float), stream);

    colsum_kernel<<<dim3(I_TOT / 128, BATCH), 256, 0, stream>>>(u, ws);
    update_kernel<<<BATCH, 256, 0, stream>>>(W, ws, out, 0, nslots);

    for (int pass = 0; pass < 3; pass++) {
        routing_kernel<<<dim3(NCHUNK_R, BATCH), 256, 0, stream>>>(u, ws, nslots);
        update_kernel<<<BATCH, 256, 0, stream>>>(W, ws, out, pass == 2 ? 2 : 1, nslots);
    }
}